// Round 1
// baseline (45.044 us; speedup 1.0000x reference)
//
#include <hip/hip_runtime.h>

#define T 32
#define BLOCK 256
#define GRID 2048

// Kernel 1: per-row loss term + deterministic per-block partial sums (double).
__global__ __launch_bounds__(BLOCK) void mel_rows(const float* __restrict__ probs,
                                                  double* __restrict__ partials,
                                                  int nrows) {
    const int tid = blockIdx.x * blockDim.x + threadIdx.x;
    const int stride = gridDim.x * blockDim.x;

    double acc = 0.0;
    for (int row = tid; row < nrows; row += stride) {
        const float4* rp = reinterpret_cast<const float4*>(probs + (size_t)row * T);
        float p[T];
        #pragma unroll
        for (int k = 0; k < T / 4; ++k) {
            float4 v = rp[k];
            p[4 * k + 0] = v.x;
            p[4 * k + 1] = v.y;
            p[4 * k + 2] = v.z;
            p[4 * k + 3] = v.w;
        }

        // suffix products of (1 - p): suf[i] = prod_{j>i} (1 - p_j)
        float suf[T];
        suf[T - 1] = 1.0f;
        #pragma unroll
        for (int i = T - 2; i >= 0; --i) suf[i] = suf[i + 1] * (1.0f - p[i + 1]);

        // forward: q_i = pre_i * suf_i ; s = (s + p_i) * q_i ; pre *= (1 - p_i)
        float pre = 1.0f;
        float s = 0.0f;
        #pragma unroll
        for (int i = 0; i < T; ++i) {
            float q = pre * suf[i];
            s = (s + p[i]) * q;
            pre *= (1.0f - p[i]);
        }
        acc += (double)s;
    }

    // wave (64-lane) reduction
    #pragma unroll
    for (int off = 32; off > 0; off >>= 1)
        acc += __shfl_down(acc, off, 64);

    __shared__ double sdata[BLOCK / 64];
    const int lane = threadIdx.x & 63;
    const int wid = threadIdx.x >> 6;
    if (lane == 0) sdata[wid] = acc;
    __syncthreads();
    if (threadIdx.x == 0) {
        double b = 0.0;
        #pragma unroll
        for (int w = 0; w < BLOCK / 64; ++w) b += sdata[w];
        partials[blockIdx.x] = b;
    }
}

// Kernel 2: deterministic reduction of GRID partials -> scalar loss.
__global__ __launch_bounds__(BLOCK) void mel_final(const double* __restrict__ partials,
                                                   float* __restrict__ out,
                                                   int nrows) {
    double acc = 0.0;
    for (int i = threadIdx.x; i < GRID; i += BLOCK) acc += partials[i];

    #pragma unroll
    for (int off = 32; off > 0; off >>= 1)
        acc += __shfl_down(acc, off, 64);

    __shared__ double sdata[BLOCK / 64];
    const int lane = threadIdx.x & 63;
    const int wid = threadIdx.x >> 6;
    if (lane == 0) sdata[wid] = acc;
    __syncthreads();
    if (threadIdx.x == 0) {
        double b = 0.0;
        #pragma unroll
        for (int w = 0; w < BLOCK / 64; ++w) b += sdata[w];
        out[0] = (float)(-b / (double)nrows);
    }
}

extern "C" void kernel_launch(void* const* d_in, const int* in_sizes, int n_in,
                              void* d_out, int out_size, void* d_ws, size_t ws_size,
                              hipStream_t stream) {
    const float* probs = (const float*)d_in[0];
    float* out = (float*)d_out;
    double* partials = (double*)d_ws;  // GRID doubles = 16 KB
    const int nrows = in_sizes[0] / T;

    mel_rows<<<GRID, BLOCK, 0, stream>>>(probs, partials, nrows);
    mel_final<<<1, BLOCK, 0, stream>>>(partials, out, nrows);
}